// Round 4
// baseline (1198.852 us; speedup 1.0000x reference)
//
#include <hip/hip_runtime.h>
#include <math.h>

#define NV 20000
#define NV_PAD 20096            // 157 * 128
#define NB 4
#define M_TOTAL (NB * NV_PAD)   // 80384 = 628 * 128
#define CF 64
#define VX 64

typedef short short8 __attribute__((ext_vector_type(8)));
typedef float floatx4 __attribute__((ext_vector_type(4)));

__device__ __forceinline__ float bf2f(unsigned int h) {
  return __uint_as_float(h << 16);
}
__device__ __forceinline__ unsigned short f2bf(float f) {
  unsigned int u = __float_as_uint(f);
  u += 0x7fffu + ((u >> 16) & 1u);   // round-to-nearest-even
  return (unsigned short)(u >> 16);
}

// ---------------- CSR construction (dst-sorted) ----------------

__global__ void hist_dst_kernel(const int* __restrict__ dst, int E, int* __restrict__ cnt) {
  int i = blockIdx.x * blockDim.x + threadIdx.x;
  if (i < E) atomicAdd(&cnt[dst[i]], 1);
}

__global__ void scan_kernel(const int* __restrict__ cnt, int* __restrict__ rowp,
                            float* __restrict__ dinv, int n) {
  __shared__ int sdata[1024];
  __shared__ int run_s;
  if (threadIdx.x == 0) run_s = 0;
  __syncthreads();
  for (int base = 0; base < n; base += 1024) {
    int i = base + (int)threadIdx.x;
    int v = (i < n) ? cnt[i] : 0;
    sdata[threadIdx.x] = v;
    __syncthreads();
    int run = run_s;
    for (int ofs = 1; ofs < 1024; ofs <<= 1) {
      int t = (threadIdx.x >= (unsigned)ofs) ? sdata[threadIdx.x - ofs] : 0;
      __syncthreads();
      sdata[threadIdx.x] += t;
      __syncthreads();
    }
    if (i < n) {
      rowp[i] = run + sdata[threadIdx.x] - v;
      dinv[i] = 1.0f / sqrtf((float)(v + 1));
    }
    if (threadIdx.x == 1023) run_s = run + sdata[1023];
    __syncthreads();
  }
  if (threadIdx.x == 0) rowp[n] = run_s;
}

__global__ void fill_csr_kernel(const int* __restrict__ src, const int* __restrict__ dst, int E,
                                const int* __restrict__ rowp, int* __restrict__ cnt2,
                                const float* __restrict__ dinv,
                                int* __restrict__ esrc, float* __restrict__ dsrc) {
  int i = blockIdx.x * blockDim.x + threadIdx.x;
  if (i < E) {
    int d = dst[i];
    int s = src[i];
    int pos = rowp[d] + atomicAdd(&cnt2[d], 1);
    esrc[pos] = s;
    dsrc[pos] = dinv[s];
  }
}

// dinv replicated per batch with pad rows = 1.0
__global__ void dinvrep_kernel(const float* __restrict__ dinv, float* __restrict__ drep) {
  int idx = blockIdx.x * blockDim.x + threadIdx.x;
  if (idx >= M_TOTAL) return;
  int n = idx % NV_PAD;
  drep[idx] = (n < NV) ? dinv[n] : 1.0f;
}

// ---------------- constant feature sample ----------------
// vn == -1 exactly (batch-min of identical copies), /1.5 -> constant grid point.
__global__ void vfeat_kernel(const float* __restrict__ feat, float* __restrict__ vfeat) {
  int t = blockIdx.x * blockDim.x + threadIdx.x;
  if (t >= NB * CF) return;
  float c = (2.0f * 0.0f / 1e-6f - 1.0f) / 1.5f;
  float pos = (c + 1.0f) * 0.5f * (float)(VX - 1);
  pos = fminf(fmaxf(pos, 0.0f), (float)(VX - 1));
  float f0 = floorf(pos);
  float w = pos - f0;
  int i0 = (int)f0;
  int i1 = i0 + 1; if (i1 > VX - 1) i1 = VX - 1;
  const float* base = feat + (size_t)t * VX * VX * VX;
  float wz[2] = {1.0f - w, w};
  int   iz[2] = {i0, i1};
  float acc = 0.0f;
  #pragma unroll
  for (int a = 0; a < 2; ++a)
    #pragma unroll
    for (int b = 0; b < 2; ++b)
      #pragma unroll
      for (int d = 0; d < 2; ++d)
        acc += wz[a] * wz[b] * wz[d] * base[(size_t)iz[a] * VX * VX + iz[b] * VX + iz[d]];
  vfeat[t] = acc;
}

__global__ void encconst_kernel(const float* __restrict__ vfeat, const float* __restrict__ W1,
                                const float* __restrict__ b1, float* __restrict__ encc) {
  int idx = blockIdx.x * blockDim.x + threadIdx.x;
  if (idx >= NB * 256) return;
  int b = idx >> 8, j = idx & 255;
  float acc = b1[j];
  #pragma unroll 8
  for (int c = 0; c < CF; ++c) acc += vfeat[b * CF + c] * W1[(3 + c) * 256 + j];
  encc[idx] = acc;
}

// x1[row][j] = relu(v[n].W1[0:3][j] + encc[b][j]) -> bf16 ; batched via blockIdx.y
__global__ void enc1_kernel(const float* __restrict__ verts, const float* __restrict__ W1,
                            const float* __restrict__ encc, unsigned short* __restrict__ out) {
  int idx = blockIdx.x * blockDim.x + threadIdx.x;
  if (idx >= NV * 256) return;
  int n = idx >> 8, j = idx & 255;
  int b = blockIdx.y;
  float acc = encc[b * 256 + j]
            + verts[n * 3 + 0] * W1[0 * 256 + j]
            + verts[n * 3 + 1] * W1[1 * 256 + j]
            + verts[n * 3 + 2] * W1[2 * 256 + j];
  out[((size_t)(b * NV_PAD + n)) * 256 + j] = f2bf(fmaxf(acc, 0.0f));
}

// ---------------- combined weight prep (fp32 [K,N] -> bf16 transposed [N,K]) ----------------
struct WPrep {
  const float* src[9];
  unsigned short* dst[9];
};

__global__ void wprep_all_kernel(WPrep wp) {
  const int WKc[9] = {256, 128, 256, 512, 1024, 512, 256, 128, 128};
  const int WNc[9] = {128, 256, 512, 1024, 512, 256, 128, 128, 64};
  const int cum[10] = {0, 32768, 65536, 196608, 720896, 1245184, 1376256, 1409024, 1425408, 1433600};
  int idx = blockIdx.x * blockDim.x + threadIdx.x;
  if (idx >= 1433600) return;
  #pragma unroll
  for (int s = 0; s < 9; ++s) {
    if (idx >= cum[s] && idx < cum[s + 1]) {
      int local = idx - cum[s];
      int k = local / WNc[s];
      int n = local - k * WNc[s];
      wp.dst[s][(size_t)n * WKc[s] + k] = f2bf(wp.src[s][local]);
      return;
    }
  }
}

// ---------------- bf16 MFMA GEMM (BK=32, double-buffered 2-phase) ----------------
// C[M_TOTAL,N] = A[M_TOTAL,K] @ Bt[N,K]^T ; 128x128 tile, 4 waves.
// 2-phase pipeline (T3 minimum recipe): stage tile t+1 into buf^1, compute buf,
// ONE __syncthreads per K-step (drains a prefetch that had the compute phase in
// flight). LDS chunk swizzle identical to the verified BK=32 scheme:
// slot (row, c) holds global k-chunk (c ^ swz(row)), swz(r)=(r+(r>>2))&3.
// XCD-chunked bijective block swizzle (T1/m204) keeps an A M-strip on one XCD.
// flags: 1=bias, 2=relu, 4=rowscale[m]
#define BM 128
#define BN 128
#define BK 32

__launch_bounds__(256, 4)
__global__ void gemm_bt_kernel(const unsigned short* __restrict__ A,
                               const unsigned short* __restrict__ Bt,
                               const float* __restrict__ bias,
                               const float* __restrict__ rowscale,
                               unsigned short* __restrict__ C,
                               int K, int Nreal, int flags) {
  __shared__ unsigned short As[2 * BM * BK];  // 2 x 8 KB
  __shared__ unsigned short Bs[2 * BM * BK];  // 2 x 8 KB
  int tid = threadIdx.x;
  int wave = tid >> 6, lane = tid & 63;

  // XCD-aware chunked remap (bijective for any nwg; m204 variant)
  unsigned int nwg = gridDim.x * gridDim.y;
  unsigned int orig = blockIdx.y * gridDim.x + blockIdx.x;
  unsigned int xcd = orig & 7u, pos = orig >> 3;
  unsigned int q = nwg >> 3, r = nwg & 7u;
  unsigned int wgid = (xcd < r ? xcd * (q + 1u) : r * (q + 1u) + (xcd - r) * q) + pos;
  unsigned int bx = wgid % gridDim.x;
  unsigned int by = wgid / gridDim.x;

  int mbase = by * BM;
  int nbase = bx * BN;
  int wm = (wave >> 1) * 64, wn = (wave & 1) * 64;

  floatx4 acc[4][4] = {};

  const int rowS = wave * 16 + (lane >> 2);                 // staging row (+ p*64)
  const int sswz = ((lane >> 2) + (lane >> 4)) & 3;         // swz(lane>>2)
  const int kseg = (((lane & 3) ^ sswz) << 3);              // swizzled global chunk (elems)
  const int fr = lane & 15, fq = lane >> 4;                 // fragment row / quad
  const int fswz = (fr + (fr >> 2)) & 3;                    // swz(fr)
  const int fchunk = ((fq ^ fswz) << 3);                    // LDS chunk for fragment reads

  const unsigned short* ga0 = A + (size_t)(mbase + rowS) * K + kseg;
  const unsigned short* gb0 = Bt + (size_t)(nbase + rowS) * K + kseg;

  auto stage = [&](int kb, int half) {
    #pragma unroll
    for (int p = 0; p < 2; ++p) {
      __builtin_amdgcn_global_load_lds(
          (const __attribute__((address_space(1))) void*)(ga0 + (size_t)(p * 64) * K + kb),
          (__attribute__((address_space(3))) void*)(As + half * 4096 + wave * 512 + p * 2048),
          16, 0, 0);
      __builtin_amdgcn_global_load_lds(
          (const __attribute__((address_space(1))) void*)(gb0 + (size_t)(p * 64) * K + kb),
          (__attribute__((address_space(3))) void*)(Bs + half * 4096 + wave * 512 + p * 2048),
          16, 0, 0);
    }
  };

  const int nt = K / BK;
  stage(0, 0);
  __syncthreads();
  int cur = 0;
  for (int t = 0; t < nt; ++t) {
    if (t + 1 < nt) stage((t + 1) * BK, cur ^ 1);   // prefetch next tile
    const unsigned short* as = As + cur * 4096;
    const unsigned short* bs = Bs + cur * 4096;
    short8 af[4], bf[4];
    #pragma unroll
    for (int i = 0; i < 4; ++i)
      af[i] = *(const short8*)(as + (wm + i * 16 + fr) * BK + fchunk);
    #pragma unroll
    for (int j = 0; j < 4; ++j)
      bf[j] = *(const short8*)(bs + (wn + j * 16 + fr) * BK + fchunk);
    #pragma unroll
    for (int i = 0; i < 4; ++i)
      #pragma unroll
      for (int j = 0; j < 4; ++j)
        acc[i][j] = __builtin_amdgcn_mfma_f32_16x16x32_bf16(af[i], bf[j], acc[i][j], 0, 0, 0);
    __syncthreads();   // drains prefetch (vmcnt 0) + protects buffer swap
    cur ^= 1;
  }

  // epilogue: C/D layout col = lane&15, row = (lane>>4)*4 + r
  #pragma unroll
  for (int j = 0; j < 4; ++j) {
    int n = nbase + wn + j * 16 + fr;
    if (n >= Nreal) continue;
    float bv = (flags & 1) ? bias[n] : 0.0f;
    #pragma unroll
    for (int i = 0; i < 4; ++i) {
      #pragma unroll
      for (int r = 0; r < 4; ++r) {
        int m = mbase + wm + i * 16 + fq * 4 + r;
        float v = acc[i][j][r];
        if (flags & 4) v *= rowscale[m];
        v += bv;
        if (flags & 2) v = fmaxf(v, 0.0f);
        C[(size_t)m * Nreal + n] = f2bf(v);
      }
    }
  }
}

// GCN post-aggregate, ALL 4 BATCHES per thread:
// out[b][n] = relu(dinv[n] * (hs[b][n] + sum_src hs[b][src]) + bias), bf16 in/out.
// esrc/rowp shared across batches; 4 independent row loads per edge (MLP=4).
__global__ void gcn_gather_kernel(const uint4* __restrict__ hs8,
                                  const float* __restrict__ bias,
                                  const float* __restrict__ dinv,
                                  const int* __restrict__ rowp, const int* __restrict__ esrc,
                                  uint4* __restrict__ out, int lc8) {
  int idx = blockIdx.x * blockDim.x + threadIdx.x;
  int C8 = 1 << lc8;
  if (idx >= NV * C8) return;
  int n = idx >> lc8;
  int j = idx & (C8 - 1);
  const size_t bstride = (size_t)NV_PAD << lc8;
  float a[NB][8];
  #pragma unroll
  for (int b = 0; b < NB; ++b) {
    uint4 u = hs8[b * bstride + ((size_t)n << lc8) + j];
    a[b][0] = bf2f(u.x & 0xffff); a[b][1] = bf2f(u.x >> 16);
    a[b][2] = bf2f(u.y & 0xffff); a[b][3] = bf2f(u.y >> 16);
    a[b][4] = bf2f(u.z & 0xffff); a[b][5] = bf2f(u.z >> 16);
    a[b][6] = bf2f(u.w & 0xffff); a[b][7] = bf2f(u.w >> 16);
  }
  int s = rowp[n], e = rowp[n + 1];
  int t = s;
  int src = (t < e) ? esrc[t] : 0;
  while (t < e) {
    size_t rb = ((size_t)src << lc8) + j;
    uint4 v0 = hs8[rb];
    uint4 v1 = hs8[rb + bstride];
    uint4 v2 = hs8[rb + 2 * bstride];
    uint4 v3 = hs8[rb + 3 * bstride];
    ++t;
    src = (t < e) ? esrc[t] : 0;
    a[0][0] += bf2f(v0.x & 0xffff); a[0][1] += bf2f(v0.x >> 16);
    a[0][2] += bf2f(v0.y & 0xffff); a[0][3] += bf2f(v0.y >> 16);
    a[0][4] += bf2f(v0.z & 0xffff); a[0][5] += bf2f(v0.z >> 16);
    a[0][6] += bf2f(v0.w & 0xffff); a[0][7] += bf2f(v0.w >> 16);
    a[1][0] += bf2f(v1.x & 0xffff); a[1][1] += bf2f(v1.x >> 16);
    a[1][2] += bf2f(v1.y & 0xffff); a[1][3] += bf2f(v1.y >> 16);
    a[1][4] += bf2f(v1.z & 0xffff); a[1][5] += bf2f(v1.z >> 16);
    a[1][6] += bf2f(v1.w & 0xffff); a[1][7] += bf2f(v1.w >> 16);
    a[2][0] += bf2f(v2.x & 0xffff); a[2][1] += bf2f(v2.x >> 16);
    a[2][2] += bf2f(v2.y & 0xffff); a[2][3] += bf2f(v2.y >> 16);
    a[2][4] += bf2f(v2.z & 0xffff); a[2][5] += bf2f(v2.z >> 16);
    a[2][6] += bf2f(v2.w & 0xffff); a[2][7] += bf2f(v2.w >> 16);
    a[3][0] += bf2f(v3.x & 0xffff); a[3][1] += bf2f(v3.x >> 16);
    a[3][2] += bf2f(v3.y & 0xffff); a[3][3] += bf2f(v3.y >> 16);
    a[3][4] += bf2f(v3.z & 0xffff); a[3][5] += bf2f(v3.z >> 16);
    a[3][6] += bf2f(v3.w & 0xffff); a[3][7] += bf2f(v3.w >> 16);
  }
  float dn = dinv[n];
  int j8 = j << 3;
  float bb[8];
  #pragma unroll
  for (int c = 0; c < 8; ++c) bb[c] = bias[j8 + c];
  #pragma unroll
  for (int b = 0; b < NB; ++b) {
    uint4 o;
    float r0 = fmaxf(a[b][0] * dn + bb[0], 0.0f);
    float r1 = fmaxf(a[b][1] * dn + bb[1], 0.0f);
    float r2 = fmaxf(a[b][2] * dn + bb[2], 0.0f);
    float r3 = fmaxf(a[b][3] * dn + bb[3], 0.0f);
    float r4 = fmaxf(a[b][4] * dn + bb[4], 0.0f);
    float r5 = fmaxf(a[b][5] * dn + bb[5], 0.0f);
    float r6 = fmaxf(a[b][6] * dn + bb[6], 0.0f);
    float r7 = fmaxf(a[b][7] * dn + bb[7], 0.0f);
    o.x = (unsigned int)f2bf(r0) | ((unsigned int)f2bf(r1) << 16);
    o.y = (unsigned int)f2bf(r2) | ((unsigned int)f2bf(r3) << 16);
    o.z = (unsigned int)f2bf(r4) | ((unsigned int)f2bf(r5) << 16);
    o.w = (unsigned int)f2bf(r6) | ((unsigned int)f2bf(r7) << 16);
    out[b * bstride + ((size_t)n << lc8) + j] = o;
  }
}

// GCN pre-aggregate (input side), ALL 4 BATCHES per thread:
// y[b][n] = dinv[n]*(dinv[n]*x[b][n] + sum_src dinv[src]*x[b][src]).
__global__ void gcn_pre_gather_kernel(const uint4* __restrict__ x8,
                                      const float* __restrict__ dinv,
                                      const int* __restrict__ rowp, const int* __restrict__ esrc,
                                      const float* __restrict__ dsrc,
                                      uint4* __restrict__ out, int lc8) {
  int idx = blockIdx.x * blockDim.x + threadIdx.x;
  int C8 = 1 << lc8;
  if (idx >= NV * C8) return;
  int n = idx >> lc8;
  int j = idx & (C8 - 1);
  const size_t bstride = (size_t)NV_PAD << lc8;
  float dn = dinv[n];
  float a[NB][8];
  #pragma unroll
  for (int b = 0; b < NB; ++b) {
    uint4 u = x8[b * bstride + ((size_t)n << lc8) + j];
    a[b][0] = dn * bf2f(u.x & 0xffff); a[b][1] = dn * bf2f(u.x >> 16);
    a[b][2] = dn * bf2f(u.y & 0xffff); a[b][3] = dn * bf2f(u.y >> 16);
    a[b][4] = dn * bf2f(u.z & 0xffff); a[b][5] = dn * bf2f(u.z >> 16);
    a[b][6] = dn * bf2f(u.w & 0xffff); a[b][7] = dn * bf2f(u.w >> 16);
  }
  int s = rowp[n], e = rowp[n + 1];
  int t = s;
  int src = (t < e) ? esrc[t] : 0;
  float w = (t < e) ? dsrc[t] : 0.0f;
  while (t < e) {
    size_t rb = ((size_t)src << lc8) + j;
    uint4 v0 = x8[rb];
    uint4 v1 = x8[rb + bstride];
    uint4 v2 = x8[rb + 2 * bstride];
    uint4 v3 = x8[rb + 3 * bstride];
    float wv = w;
    ++t;
    src = (t < e) ? esrc[t] : 0;
    w = (t < e) ? dsrc[t] : 0.0f;
    a[0][0] += wv * bf2f(v0.x & 0xffff); a[0][1] += wv * bf2f(v0.x >> 16);
    a[0][2] += wv * bf2f(v0.y & 0xffff); a[0][3] += wv * bf2f(v0.y >> 16);
    a[0][4] += wv * bf2f(v0.z & 0xffff); a[0][5] += wv * bf2f(v0.z >> 16);
    a[0][6] += wv * bf2f(v0.w & 0xffff); a[0][7] += wv * bf2f(v0.w >> 16);
    a[1][0] += wv * bf2f(v1.x & 0xffff); a[1][1] += wv * bf2f(v1.x >> 16);
    a[1][2] += wv * bf2f(v1.y & 0xffff); a[1][3] += wv * bf2f(v1.y >> 16);
    a[1][4] += wv * bf2f(v1.z & 0xffff); a[1][5] += wv * bf2f(v1.z >> 16);
    a[1][6] += wv * bf2f(v1.w & 0xffff); a[1][7] += wv * bf2f(v1.w >> 16);
    a[2][0] += wv * bf2f(v2.x & 0xffff); a[2][1] += wv * bf2f(v2.x >> 16);
    a[2][2] += wv * bf2f(v2.y & 0xffff); a[2][3] += wv * bf2f(v2.y >> 16);
    a[2][4] += wv * bf2f(v2.z & 0xffff); a[2][5] += wv * bf2f(v2.z >> 16);
    a[2][6] += wv * bf2f(v2.w & 0xffff); a[2][7] += wv * bf2f(v2.w >> 16);
    a[3][0] += wv * bf2f(v3.x & 0xffff); a[3][1] += wv * bf2f(v3.x >> 16);
    a[3][2] += wv * bf2f(v3.y & 0xffff); a[3][3] += wv * bf2f(v3.y >> 16);
    a[3][4] += wv * bf2f(v3.z & 0xffff); a[3][5] += wv * bf2f(v3.z >> 16);
    a[3][6] += wv * bf2f(v3.w & 0xffff); a[3][7] += wv * bf2f(v3.w >> 16);
  }
  #pragma unroll
  for (int b = 0; b < NB; ++b) {
    uint4 o;
    o.x = (unsigned int)f2bf(a[b][0] * dn) | ((unsigned int)f2bf(a[b][1] * dn) << 16);
    o.y = (unsigned int)f2bf(a[b][2] * dn) | ((unsigned int)f2bf(a[b][3] * dn) << 16);
    o.z = (unsigned int)f2bf(a[b][4] * dn) | ((unsigned int)f2bf(a[b][5] * dn) << 16);
    o.w = (unsigned int)f2bf(a[b][6] * dn) | ((unsigned int)f2bf(a[b][7] * dn) << 16);
    out[b * bstride + ((size_t)n << lc8) + j] = o;
  }
}

// final head, batched via blockIdx.y
__global__ void head3_kernel(const unsigned short* __restrict__ d, const float* __restrict__ hW3,
                             const float* __restrict__ hb3, const float* __restrict__ verts,
                             float* __restrict__ out) {
  int idx = blockIdx.x * blockDim.x + threadIdx.x;
  if (idx >= NV * 3) return;
  int n = idx / 3;
  int k = idx - n * 3;
  int b = blockIdx.y;
  const unsigned short* drow = d + ((size_t)(b * NV_PAD + n)) * 64;
  float acc = hb3[k];
  #pragma unroll 8
  for (int c = 0; c < 64; ++c) acc += bf2f(drow[c]) * hW3[c * 3 + k];
  float t = tanhf(acc);
  t = fminf(fmaxf(t, -2.5f), 2.5f);
  out[(size_t)b * NV * 3 + idx] = verts[idx] + t;
}

// ---------------- launch ----------------

static inline void launch_gemm(const unsigned short* A, const unsigned short* Bt,
                               const float* bias, const float* rowscale, unsigned short* C,
                               int N, int K, int flags, hipStream_t stream) {
  int Npad = (N + BN - 1) / BN * BN;
  dim3 grid(Npad / BN, M_TOTAL / BM);
  gemm_bt_kernel<<<grid, 256, 0, stream>>>(A, Bt, bias, rowscale, C, K, N, flags);
}

extern "C" void kernel_launch(void* const* d_in, const int* in_sizes, int n_in,
                              void* d_out, int out_size, void* d_ws, size_t ws_size,
                              hipStream_t stream) {
  const float* features = (const float*)d_in[0];
  const float* vertices = (const float*)d_in[1];
  const int* edge_index = (const int*)d_in[2];
  const int E = in_sizes[2] / 2;
  const int* esrc_in = edge_index;       // edge_index[0] = src
  const int* edst_in = edge_index + E;   // edge_index[1] = dst
  const float* enc_W1 = (const float*)d_in[3];
  const float* enc_b1 = (const float*)d_in[4];
  const float* enc_W2 = (const float*)d_in[5];
  const float* enc_b2 = (const float*)d_in[6];
  const float* gW[6]; const float* gb[6];
  for (int i = 0; i < 6; ++i) { gW[i] = (const float*)d_in[7 + 2 * i]; gb[i] = (const float*)d_in[8 + 2 * i]; }
  const float* hW1 = (const float*)d_in[19]; const float* hb1 = (const float*)d_in[20];
  const float* hW2 = (const float*)d_in[21]; const float* hb2 = (const float*)d_in[22];
  const float* hW3 = (const float*)d_in[23]; const float* hb3 = (const float*)d_in[24];

  char* ws = (char*)d_ws;
  size_t off = 0;
  auto alloc = [&](size_t bytes) -> void* {
    void* p = (void*)(ws + off);
    off += (bytes + 255) & ~(size_t)255;
    return p;
  };
  unsigned short* bufA = (unsigned short*)alloc((size_t)M_TOTAL * 1024 * 2);
  unsigned short* bufB = (unsigned short*)alloc((size_t)M_TOTAL * 1024 * 2);
  float* dinv  = (float*)alloc(NV * sizeof(float));
  float* drep  = (float*)alloc(M_TOTAL * sizeof(float));
  float* vfeat = (float*)alloc(NB * CF * sizeof(float));
  float* encc  = (float*)alloc(NB * 256 * sizeof(float));
  int* cnt  = (int*)alloc(NV * sizeof(int));
  int* rowp = (int*)alloc((NV + 1) * sizeof(int));
  int* cnt2 = (int*)alloc(NV * sizeof(int));
  int* esrc = (int*)alloc((size_t)E * sizeof(int));
  float* dsrc = (float*)alloc((size_t)E * sizeof(float));
  // bf16 transposed weights (rows padded to >=128)
  const size_t wtsz[9] = {128 * 256, 256 * 128, 512 * 256, 1024 * 512, 512 * 1024,
                          256 * 512, 128 * 256, 128 * 128, 128 * 128};
  unsigned short* wt[9];
  {
    size_t tot = 0;
    for (int i = 0; i < 9; ++i) tot += wtsz[i];
    unsigned short* base = (unsigned short*)alloc(tot * 2);
    size_t o = 0;
    for (int i = 0; i < 9; ++i) { wt[i] = base + o; o += wtsz[i]; }
  }

  hipMemsetAsync(cnt,  0, NV * sizeof(int), stream);
  hipMemsetAsync(cnt2, 0, NV * sizeof(int), stream);
  hist_dst_kernel<<<(E + 255) / 256, 256, 0, stream>>>(edst_in, E, cnt);
  scan_kernel<<<1, 1024, 0, stream>>>(cnt, rowp, dinv, NV);
  fill_csr_kernel<<<(E + 255) / 256, 256, 0, stream>>>(esrc_in, edst_in, E, rowp, cnt2,
                                                       dinv, esrc, dsrc);
  dinvrep_kernel<<<(M_TOTAL + 255) / 256, 256, 0, stream>>>(dinv, drep);
  vfeat_kernel<<<1, 256, 0, stream>>>(features, vfeat);
  encconst_kernel<<<NB, 256, 0, stream>>>(vfeat, enc_W1, enc_b1, encc);

  WPrep wp;
  const float* wsrc[9] = {enc_W2, gW[0], gW[1], gW[2], gW[3], gW[4], gW[5], hW1, hW2};
  for (int i = 0; i < 9; ++i) { wp.src[i] = wsrc[i]; wp.dst[i] = wt[i]; }
  wprep_all_kernel<<<(1433600 + 255) / 256, 256, 0, stream>>>(wp);

  const int gout[6] = {256, 512, 1024, 512, 256, 128};
  const int gin[6]  = {128, 256, 512, 1024, 512, 256};
  const int inlc8[6] = {4, 5, 6, 7, 6, 5};   // log2(Cin/8)
  const int outlc8[6] = {5, 6, 7, 6, 5, 4};  // log2(Cout/8)
  const int inside[6] = {1, 1, 1, 0, 0, 0};  // aggregate on min(Cin, Cout) side

  // enc layer 1 (all batches) -> bufA [M_TOTAL,256]
  dim3 e1grid((NV * 256 + 255) / 256, NB);
  enc1_kernel<<<e1grid, 256, 0, stream>>>(vertices, enc_W1, encc, bufA);
  // enc layer 2 -> bufB [M_TOTAL,128]
  launch_gemm(bufA, wt[0], enc_b2, nullptr, bufB, 128, 256, 1 | 2, stream);

  unsigned short* x = bufB;
  unsigned short* h = bufA;
  for (int i = 0; i < 6; ++i) {
    if (inside[i]) {
      // y = N x  (gather on input, Cin channels), then out = relu(y @ W + b)
      int total8 = NV * (gin[i] / 8);
      gcn_pre_gather_kernel<<<(total8 + 255) / 256, 256, 0, stream>>>(
          (const uint4*)x, dinv, rowp, esrc, dsrc, (uint4*)h, inlc8[i]);
      launch_gemm(h, wt[1 + i], gb[i], nullptr, x, gout[i], gin[i], 1 | 2, stream);
    } else {
      // hs = (x @ gW) * dinv[row], then out = relu(dinv*(hs[n]+sum hs[src]) + b)
      launch_gemm(x, wt[1 + i], nullptr, drep, h, gout[i], gin[i], 4, stream);
      int total8 = NV * (gout[i] / 8);
      gcn_gather_kernel<<<(total8 + 255) / 256, 256, 0, stream>>>(
          (const uint4*)h, gb[i], dinv, rowp, esrc, (uint4*)x, outlc8[i]);
    }
  }
  // head
  launch_gemm(x, wt[7], hb1, nullptr, h, 128, 128, 1 | 2, stream);  // bufA [M_TOTAL,128]
  launch_gemm(h, wt[8], hb2, nullptr, x, 64, 128, 1 | 2, stream);   // bufB [M_TOTAL,64]
  dim3 hgrid((NV * 3 + 255) / 256, NB);
  head3_kernel<<<hgrid, 256, 0, stream>>>(x, hW3, hb3, vertices, (float*)d_out);
}